// Round 1
// baseline (648.260 us; speedup 1.0000x reference)
//
#include <hip/hip_runtime.h>

// DiffSelfAttention on MI355X (gfx950).
// Strategy: fp32-accurate via bf16 hi/lo 3-term split MFMA (no fp32 MFMA on CDNA4).
// Pipeline: [split/transpose preproc] -> GEMM1(qkv, split epilogue) ->
//           fused dual flash-attention (+lambda combine + RMS norm) -> GEMM2(proj, fp32 out)
// All bf16 intermediates stored pre-swizzled (XOR k-bits by row) so LDS ds_read_b128
// fragment reads are ~2-way-conflict; global_load_lds copies linearly (rule 21).

typedef unsigned short u16;
typedef __attribute__((ext_vector_type(8))) short bf16x8;
typedef __attribute__((ext_vector_type(4))) float f32x4;

#define MFMA16(a, b, c) __builtin_amdgcn_mfma_f32_16x16x32_bf16((a), (b), (c), 0, 0, 0)

#define LAMBDA_INIT_F 0.35550906759096926f
#define ONE_MINUS_LI_F 0.64449093240903074f

__device__ __forceinline__ u16 f2bf(float f) {
  union { float f; unsigned u; } v; v.f = f;
  unsigned r = v.u + 0x7fffu + ((v.u >> 16) & 1u);  // RNE
  return (u16)(r >> 16);
}
__device__ __forceinline__ float bf2f(u16 h) {
  union { unsigned u; float f; } v; v.u = ((unsigned)h) << 16;
  return v.f;
}
// swizzles: XOR bits 3..4 (64B rows / 32-elem chunks) or 3..5 (128B rows / 64-elem chunks)
__device__ __forceinline__ int sw3(int row) { return (row & 3) << 3; }
__device__ __forceinline__ int sw7(int row) { return (row & 7) << 3; }

__device__ __forceinline__ void gload16(const u16* g, u16* l) {
  __builtin_amdgcn_global_load_lds((const __attribute__((address_space(1))) void*)g,
                                   (__attribute__((address_space(3))) void*)l,
                                   16, 0, 0);
}

// ---------------- preprocessing ----------------

// lam = exp(sum lq1*lk1) - exp(sum lq2*lk2) + LAMBDA_INIT
__global__ void lam_kernel(const float* __restrict__ q1, const float* __restrict__ k1,
                           const float* __restrict__ q2, const float* __restrict__ k2,
                           float* __restrict__ out) {
  int l = threadIdx.x;  // 64
  float p1 = q1[l] * k1[l];
  float p2 = q2[l] * k2[l];
#pragma unroll
  for (int m = 32; m >= 1; m >>= 1) {
    p1 += __shfl_xor(p1, m, 64);
    p2 += __shfl_xor(p2, m, 64);
  }
  if (l == 0) out[0] = expf(p1) - expf(p2) + LAMBDA_INIT_F;
}

// x [2048][2048] f32 -> hi/lo bf16, column-swizzled by sw3(row)
__global__ void split_x_kernel(const float* __restrict__ X, u16* __restrict__ H,
                               u16* __restrict__ L) {
  int idx = blockIdx.x * 256 + threadIdx.x;
  int t = idx >> 9;              // 512 threads per row of 2048
  int c0 = (idx & 511) << 2;
  float4 v = *reinterpret_cast<const float4*>(X + ((size_t)t << 11) + c0);
  float vv[4] = {v.x, v.y, v.z, v.w};
  int s = sw3(t);
  size_t base = (size_t)t << 11;
#pragma unroll
  for (int j = 0; j < 4; ++j) {
    int c = (c0 + j) ^ s;
    u16 h = f2bf(vv[j]);
    H[base + c] = h;
    L[base + c] = f2bf(vv[j] - bf2f(h));
  }
}

// W [K][N] f32 -> W^T [N][K] hi/lo bf16, column(k)-swizzled by sw3(n)
__global__ void transpose_split_kernel(const float* __restrict__ W, u16* __restrict__ TH,
                                       u16* __restrict__ TL, int K, int N) {
  __shared__ float tile[64][65];
  int bk = blockIdx.x * 64, bn = blockIdx.y * 64;
  for (int i = threadIdx.x; i < 64 * 64; i += 256) {
    int r = i >> 6, c = i & 63;
    tile[r][c] = W[(size_t)(bk + r) * N + bn + c];
  }
  __syncthreads();
  for (int i = threadIdx.x; i < 64 * 64; i += 256) {
    int r = i >> 6, c = i & 63;  // out row n = bn+r, out col k = bk+c
    float v = tile[c][r];
    int n = bn + r, k = bk + c;
    u16 h = f2bf(v);
    float lo = v - bf2f(h);
    size_t o = (size_t)n * K + (k ^ sw3(n));
    TH[o] = h;
    TL[o] = f2bf(lo);
  }
}

// ---------------- bf16x3 GEMM ----------------
// C[M][N] = A@B with A hi/lo [M][K] and B^T hi/lo [N][K], all sw3-swizzled.
// EPI 0: split epilogue -> qk (q plain, k sw7-swizzled) + vT (sw3-swizzled) for attention
// EPI 1: fp32 epilogue -> outp
template <int EPI>
__global__ __launch_bounds__(256, 2) void gemm_bf16x3(
    const u16* __restrict__ Agh, const u16* __restrict__ Agl, const u16* __restrict__ Bgh,
    const u16* __restrict__ Bgl, int N, int K, u16* __restrict__ qk_h, u16* __restrict__ qk_l,
    u16* __restrict__ vt_h, u16* __restrict__ vt_l, float* __restrict__ outp) {
  __shared__ __align__(16) u16 LA[4][128][32];  // 0:Ah 1:Al 2:Bh 3:Bl (32 KB)
  const int tid = threadIdx.x;
  const int w = tid >> 6, lane = tid & 63;
  const int lr = lane & 15, kg = lane >> 4;
  const int bn0 = blockIdx.x * 128, bm0 = blockIdx.y * 128;
  const int wm = (w >> 1) * 64, wn = (w & 1) * 64;

  // wave w stages LA[w]; 8 chunks of 1KB (16 rows x 64B)
  const u16* gsrc = (w == 0) ? Agh : (w == 1) ? Agl : (w == 2) ? Bgh : Bgl;
  const int tbase = (w < 2) ? bm0 : bn0;
  const int srow = lane >> 2;
  const int scol = (lane & 3) << 3;
  const u16* gp = gsrc + (size_t)(tbase + srow) * K + scol;
  u16* lw = &LA[w][0][0];

  f32x4 acc[4][4];
  const f32x4 VZ = {0.f, 0.f, 0.f, 0.f};
#pragma unroll
  for (int m = 0; m < 4; ++m)
#pragma unroll
    for (int n = 0; n < 4; ++n) acc[m][n] = VZ;

  for (int k0 = 0; k0 < K; k0 += 32) {
    __syncthreads();  // previous tile's reads done
#pragma unroll
    for (int c = 0; c < 8; ++c) gload16(gp + (size_t)c * 16 * K + k0, lw + c * 512);
    __syncthreads();  // staging drained (vmcnt(0) before barrier)

    bf16x8 ah[4], al[4], bh[4], bl[4];
#pragma unroll
    for (int m = 0; m < 4; ++m) {
      int row = wm + m * 16 + lr;
      int off = (row << 5) + ((kg << 3) ^ sw3(row));
      ah[m] = *reinterpret_cast<const bf16x8*>(&LA[0][0][0] + off);
      al[m] = *reinterpret_cast<const bf16x8*>(&LA[1][0][0] + off);
    }
#pragma unroll
    for (int n = 0; n < 4; ++n) {
      int row = wn + n * 16 + lr;
      int off = (row << 5) + ((kg << 3) ^ sw3(row));
      bh[n] = *reinterpret_cast<const bf16x8*>(&LA[2][0][0] + off);
      bl[n] = *reinterpret_cast<const bf16x8*>(&LA[3][0][0] + off);
    }
#pragma unroll
    for (int m = 0; m < 4; ++m)
#pragma unroll
      for (int n = 0; n < 4; ++n) {
        acc[m][n] = MFMA16(ah[m], bh[n], acc[m][n]);
        acc[m][n] = MFMA16(ah[m], bl[n], acc[m][n]);
        acc[m][n] = MFMA16(al[m], bh[n], acc[m][n]);
      }
  }

#pragma unroll
  for (int m = 0; m < 4; ++m) {
#pragma unroll
    for (int n = 0; n < 4; ++n) {
#pragma unroll
      for (int r = 0; r < 4; ++r) {
        int row = bm0 + wm + m * 16 + (kg << 2) + r;  // C/D: row=(lane>>4)*4+reg
        int col = bn0 + wn + n * 16 + lr;             //      col=lane&15
        float v = acc[m][n][r];
        if (EPI == 0) {
          u16 hh = f2bf(v);
          u16 ll = f2bf(v - bf2f(hh));
          if (col < 4096) {  // q (plain) and k (sw7 by t, 64-col head slices)
            int cc = (col < 2048) ? col : (2048 + ((col - 2048) ^ sw7(row)));
            qk_h[((size_t)row << 12) + cc] = hh;
            qk_l[((size_t)row << 12) + cc] = ll;
          } else {  // v -> transposed [vc][t], t sw3-swizzled by vc
            int vc = col - 4096;
            int tt = row ^ sw3(vc);
            vt_h[((size_t)vc << 11) + tt] = hh;
            vt_l[((size_t)vc << 11) + tt] = ll;
          }
        } else {
          outp[(size_t)row * N + col] = v;
        }
      }
    }
  }
}

// ---------------- fused dual flash-attention + lambda-combine + RMS norm ----------------
// grid: (T/64, 16 heads), 4 waves; wave owns 16 q-rows. KB=32 keys per tile.
__global__ __launch_bounds__(256, 2) void diff_attn_kernel(
    const u16* __restrict__ qk_h, const u16* __restrict__ qk_l, const u16* __restrict__ vt_h,
    const u16* __restrict__ vt_l, const float* __restrict__ lam_p,
    const float* __restrict__ rms_scale, u16* __restrict__ attn_h, u16* __restrict__ attn_l) {
  __shared__ __align__(16) u16 KL[4][32][64];    // K1h K1l K2h K2l (16 KB)
  __shared__ __align__(16) u16 VL[2][128][32];   // V^T hi, lo (16 KB)
  __shared__ __align__(16) u16 PL[4][4][16][32]; // per-wave P: p1h p1l p2h p2l (16 KB)

  const int tid = threadIdx.x;
  const int w = tid >> 6, lane = tid & 63;
  const int lr = lane & 15, kg = lane >> 4;
  const int h = blockIdx.y;
  const int qb = blockIdx.x * 64 + w * 16;
  const float lam = lam_p[0];
  const f32x4 VZ = {0.f, 0.f, 0.f, 0.f};

  // Q fragments (A-operand), held in registers all kernel: [stream][hi/lo][kchunk]
  bf16x8 qf[2][2][2];
  {
    const size_t qrb = ((size_t)(qb + lr)) << 12;
#pragma unroll
    for (int s = 0; s < 2; ++s) {
      int qo = h * 64 + s * 1024;  // q1: head h; q2: head 16+h
#pragma unroll
      for (int kc = 0; kc < 2; ++kc) {
        qf[s][0][kc] = *reinterpret_cast<const bf16x8*>(qk_h + qrb + qo + kc * 32 + (kg << 3));
        qf[s][1][kc] = *reinterpret_cast<const bf16x8*>(qk_l + qrb + qo + kc * 32 + (kg << 3));
      }
    }
  }

  f32x4 o1[8], o2[8];
#pragma unroll
  for (int n = 0; n < 8; ++n) { o1[n] = VZ; o2[n] = VZ; }
  float m1[4], l1[4], m2[4], l2[4];
#pragma unroll
  for (int r = 0; r < 4; ++r) { m1[r] = m2[r] = -1e30f; l1[r] = l2[r] = 0.f; }

  // staging roles: wave w stages KL[w] (k1h/k1l/k2h/k2l); waves 0,1->VL[0] (hi), 2,3->VL[1] (lo)
  const u16* ksrc = (w & 1) ? qk_l : qk_h;
  const int koff = 2048 + h * 64 + (w >> 1) * 1024;
  const int k_srow = lane >> 3, k_scol = (lane & 7) << 3;  // 8 rows x 128B per 1KB chunk
  const u16* vsrc = (w >> 1) ? vt_l : vt_h;
  const int vc0 = (w & 1) * 4;
  const int v_srow = lane >> 2, v_scol = (lane & 3) << 3;  // 16 rows x 64B per 1KB chunk
  u16* klw = &KL[w][0][0];
  u16* vlw = &VL[w >> 1][0][0];

  // online-softmax update for one stream; writes P hi/lo (swizzled) into PL[w][pidx..pidx+1]
  auto smx = [&](f32x4 (&sf)[2], float (&m)[4], float (&l)[4], f32x4 (&o)[8], int pidx) {
    float sv[2][4];
#pragma unroll
    for (int n = 0; n < 2; ++n)
#pragma unroll
      for (int r = 0; r < 4; ++r) sv[n][r] = sf[n][r] * 0.125f;  // scale=1/sqrt(64)
#pragma unroll
    for (int r = 0; r < 4; ++r) {
      float t = fmaxf(sv[0][r], sv[1][r]);
      t = fmaxf(t, __shfl_xor(t, 1, 64));
      t = fmaxf(t, __shfl_xor(t, 2, 64));
      t = fmaxf(t, __shfl_xor(t, 4, 64));
      t = fmaxf(t, __shfl_xor(t, 8, 64));
      float mn = fmaxf(m[r], t);
      float corr = __expf(m[r] - mn);
      m[r] = mn;
      l[r] *= corr;
#pragma unroll
      for (int n = 0; n < 8; ++n) o[n][r] *= corr;
    }
    float ps[4] = {0.f, 0.f, 0.f, 0.f};
#pragma unroll
    for (int n = 0; n < 2; ++n)
#pragma unroll
      for (int r = 0; r < 4; ++r) {
        float p = __expf(sv[n][r] - m[r]);
        ps[r] += p;
        u16 ph = f2bf(p);
        u16 plo = f2bf(p - bf2f(ph));
        int prow = (kg << 2) + r;
        int pcol = (n * 16 + lr) ^ sw3(prow);
        PL[w][pidx + 0][prow][pcol] = ph;
        PL[w][pidx + 1][prow][pcol] = plo;
      }
#pragma unroll
    for (int r = 0; r < 4; ++r) {
      float t = ps[r];
      t += __shfl_xor(t, 1, 64);
      t += __shfl_xor(t, 2, 64);
      t += __shfl_xor(t, 4, 64);
      t += __shfl_xor(t, 8, 64);
      l[r] += t;
    }
  };

  for (int kt = 0; kt < 2048; kt += 32) {
    __syncthreads();  // previous tile's KL/VL reads complete
#pragma unroll
    for (int c = 0; c < 4; ++c)
      gload16(ksrc + (((size_t)(kt + c * 8 + k_srow)) << 12) + koff + k_scol, klw + c * 512);
#pragma unroll
    for (int c = 0; c < 4; ++c) {
      int ch = vc0 + c;
      gload16(vsrc + (((size_t)(h * 128 + ch * 16 + v_srow)) << 11) + kt + v_scol,
              vlw + ch * 512);
    }
    __syncthreads();  // staging drained

    // scores: S = Q K^T via bf16x3 (QhKh + QhKl + QlKh)
    f32x4 s1[2], s2[2];
#pragma unroll
    for (int n = 0; n < 2; ++n) { s1[n] = VZ; s2[n] = VZ; }
#pragma unroll
    for (int n = 0; n < 2; ++n) {
      int key = n * 16 + lr;
#pragma unroll
      for (int kc = 0; kc < 2; ++kc) {
        int off = (key << 6) + (((kc << 5) + (kg << 3)) ^ sw7(key));
        bf16x8 k1h = *reinterpret_cast<const bf16x8*>(&KL[0][0][0] + off);
        bf16x8 k1l = *reinterpret_cast<const bf16x8*>(&KL[1][0][0] + off);
        bf16x8 k2h = *reinterpret_cast<const bf16x8*>(&KL[2][0][0] + off);
        bf16x8 k2l = *reinterpret_cast<const bf16x8*>(&KL[3][0][0] + off);
        s1[n] = MFMA16(qf[0][0][kc], k1h, s1[n]);
        s1[n] = MFMA16(qf[0][0][kc], k1l, s1[n]);
        s1[n] = MFMA16(qf[0][1][kc], k1h, s1[n]);
        s2[n] = MFMA16(qf[1][0][kc], k2h, s2[n]);
        s2[n] = MFMA16(qf[1][0][kc], k2l, s2[n]);
        s2[n] = MFMA16(qf[1][1][kc], k2h, s2[n]);
      }
    }

    smx(s1, m1, l1, o1, 0);
    smx(s2, m2, l2, o2, 2);

    // PV: O += P V via bf16x3 (PhVh + PhVl + PlVh)
    {
      int pboff = ((kg << 3) ^ sw3(lr));
      bf16x8 p1h = *reinterpret_cast<const bf16x8*>(&PL[w][0][lr][0] + pboff);
      bf16x8 p1l = *reinterpret_cast<const bf16x8*>(&PL[w][1][lr][0] + pboff);
      bf16x8 p2h = *reinterpret_cast<const bf16x8*>(&PL[w][2][lr][0] + pboff);
      bf16x8 p2l = *reinterpret_cast<const bf16x8*>(&PL[w][3][lr][0] + pboff);
#pragma unroll
      for (int n = 0; n < 8; ++n) {
        int vd = n * 16 + lr;
        int off = (vd << 5) + ((kg << 3) ^ sw3(vd));
        bf16x8 vh = *reinterpret_cast<const bf16x8*>(&VL[0][0][0] + off);
        bf16x8 vl = *reinterpret_cast<const bf16x8*>(&VL[1][0][0] + off);
        o1[n] = MFMA16(p1h, vh, o1[n]);
        o1[n] = MFMA16(p1h, vl, o1[n]);
        o1[n] = MFMA16(p1l, vh, o1[n]);
        o2[n] = MFMA16(p2h, vh, o2[n]);
        o2[n] = MFMA16(p2h, vl, o2[n]);
        o2[n] = MFMA16(p2l, vh, o2[n]);
      }
    }
  }

  // epilogue: a1 - lam*a2, RMS over 128, * rms_scale * (1-LAMBDA_INIT); split-write for GEMM2
  float nsc[4];
  {
    float il1[4], il2[4], ss[4];
#pragma unroll
    for (int r = 0; r < 4; ++r) { il1[r] = 1.f / l1[r]; il2[r] = 1.f / l2[r]; ss[r] = 0.f; }
#pragma unroll
    for (int n = 0; n < 8; ++n)
#pragma unroll
      for (int r = 0; r < 4; ++r) {
        float v = o1[n][r] * il1[r] - lam * (o2[n][r] * il2[r]);
        o1[n][r] = v;
        ss[r] += v * v;
      }
#pragma unroll
    for (int r = 0; r < 4; ++r) {
      float t = ss[r];
      t += __shfl_xor(t, 1, 64);
      t += __shfl_xor(t, 2, 64);
      t += __shfl_xor(t, 4, 64);
      t += __shfl_xor(t, 8, 64);
      nsc[r] = rsqrtf(t * (1.f / 128.f) + 1e-6f) * ONE_MINUS_LI_F;
    }
  }
#pragma unroll
  for (int n = 0; n < 8; ++n) {
    float rs = rms_scale[n * 16 + lr];
#pragma unroll
    for (int r = 0; r < 4; ++r) {
      int row = qb + (kg << 2) + r;
      int col = h * 128 + n * 16 + lr;
      float v = o1[n][r] * nsc[r] * rs;
      u16 hh = f2bf(v);
      int cc = col ^ sw3(row);
      attn_h[((size_t)row << 11) + cc] = hh;
      attn_l[((size_t)row << 11) + cc] = f2bf(v - bf2f(hh));
    }
  }
}

// ---------------- launch ----------------

extern "C" void kernel_launch(void* const* d_in, const int* in_sizes, int n_in, void* d_out,
                              int out_size, void* d_ws, size_t ws_size, hipStream_t stream) {
  (void)in_sizes; (void)n_in; (void)out_size;
  const float* x = (const float*)d_in[0];
  const float* wqkv = (const float*)d_in[1];
  const float* wprj = (const float*)d_in[2];
  const float* lq1 = (const float*)d_in[3];
  const float* lk1 = (const float*)d_in[4];
  const float* lq2 = (const float*)d_in[5];
  const float* lk2 = (const float*)d_in[6];
  const float* rms = (const float*)d_in[7];
  float* out = (float*)d_out;

  char* p = (char*)d_ws;
  auto take = [&](size_t n) { char* r = p; p += (n + 255) & ~(size_t)255; return r; };
  float* lam = (float*)take(256);
  u16* x_h = (u16*)take(2048ull * 2048 * 2);
  u16* x_l = (u16*)take(2048ull * 2048 * 2);
  u16* wqT_h = (u16*)take(6144ull * 2048 * 2);
  u16* wqT_l = (u16*)take(6144ull * 2048 * 2);
  u16* wpT_h = (u16*)take(2048ull * 2048 * 2);
  u16* wpT_l = (u16*)take(2048ull * 2048 * 2);
  u16* qk_h = (u16*)take(2048ull * 4096 * 2);
  u16* qk_l = (u16*)take(2048ull * 4096 * 2);
  u16* vt_h = (u16*)take(2048ull * 2048 * 2);
  u16* vt_l = (u16*)take(2048ull * 2048 * 2);
  u16* at_h = (u16*)take(2048ull * 2048 * 2);
  u16* at_l = (u16*)take(2048ull * 2048 * 2);
  if ((size_t)(p - (char*)d_ws) > ws_size) return;  // ws too small: fail loudly via mismatch

  lam_kernel<<<1, 64, 0, stream>>>(lq1, lk1, lq2, lk2, lam);
  split_x_kernel<<<4096, 256, 0, stream>>>(x, x_h, x_l);
  transpose_split_kernel<<<dim3(32, 96), 256, 0, stream>>>(wqkv, wqT_h, wqT_l, 2048, 6144);
  transpose_split_kernel<<<dim3(32, 32), 256, 0, stream>>>(wprj, wpT_h, wpT_l, 2048, 2048);

  // qkv = x @ w_qkv  (M=2048, N=6144, K=2048), split epilogue -> qk + v^T
  gemm_bf16x3<0><<<dim3(48, 16), 256, 0, stream>>>(x_h, x_l, wqT_h, wqT_l, 6144, 2048, qk_h,
                                                   qk_l, vt_h, vt_l, nullptr);
  // dual flash attention + combine + RMS
  diff_attn_kernel<<<dim3(32, 16), 256, 0, stream>>>(qk_h, qk_l, vt_h, vt_l, lam, rms, at_h,
                                                     at_l);
  // out = attn @ w_proj (M=N=K=2048), fp32 epilogue
  gemm_bf16x3<1><<<dim3(16, 16), 256, 0, stream>>>(at_h, at_l, wpT_h, wpT_l, 2048, 2048,
                                                   nullptr, nullptr, nullptr, nullptr, out);
}

// Round 2
// 421.911 us; speedup vs baseline: 1.5365x; 1.5365x over previous
//
#include <hip/hip_runtime.h>

// DiffSelfAttention on MI355X (gfx950).
// Precision scheme: GEMMs 2-term ((Ah+Al)*Bh); attention plain-bf16 (Q,K,V,P hi-only).
// Error budget: each dropped low-order term ~1e-3 sigma on output vs measured 0.0156 absmax.
// Attention: KB=64 key tiles, sw7-swizzled K and V^T LDS (128B rows), defer-max THR=8,
// P hi-only in rotation-swizzled LDS.

typedef unsigned short u16;
typedef __attribute__((ext_vector_type(8))) short bf16x8;
typedef __attribute__((ext_vector_type(4))) float f32x4;

#define MFMA16(a, b, c) __builtin_amdgcn_mfma_f32_16x16x32_bf16((a), (b), (c), 0, 0, 0)

#define LAMBDA_INIT_F 0.35550906759096926f
#define ONE_MINUS_LI_F 0.64449093240903074f

__device__ __forceinline__ u16 f2bf(float f) {
  union { float f; unsigned u; } v; v.f = f;
  unsigned r = v.u + 0x7fffu + ((v.u >> 16) & 1u);  // RNE
  return (u16)(r >> 16);
}
__device__ __forceinline__ float bf2f(u16 h) {
  union { unsigned u; float f; } v; v.u = ((unsigned)h) << 16;
  return v.f;
}
// XOR-swizzles on element index bits 3..4 / 3..5
__device__ __forceinline__ int sw3(int row) { return (row & 3) << 3; }
__device__ __forceinline__ int sw7(int row) { return (row & 7) << 3; }

__device__ __forceinline__ void gload16(const u16* g, u16* l) {
  __builtin_amdgcn_global_load_lds((const __attribute__((address_space(1))) void*)g,
                                   (__attribute__((address_space(3))) void*)l,
                                   16, 0, 0);
}

// ---------------- preprocessing ----------------

__global__ void lam_kernel(const float* __restrict__ q1, const float* __restrict__ k1,
                           const float* __restrict__ q2, const float* __restrict__ k2,
                           float* __restrict__ out) {
  int l = threadIdx.x;  // 64
  float p1 = q1[l] * k1[l];
  float p2 = q2[l] * k2[l];
#pragma unroll
  for (int m = 32; m >= 1; m >>= 1) {
    p1 += __shfl_xor(p1, m, 64);
    p2 += __shfl_xor(p2, m, 64);
  }
  if (l == 0) out[0] = expf(p1) - expf(p2) + LAMBDA_INIT_F;
}

// x [2048][2048] f32 -> hi/lo bf16, column-swizzled by sw3(row)
__global__ void split_x_kernel(const float* __restrict__ X, u16* __restrict__ H,
                               u16* __restrict__ L) {
  int idx = blockIdx.x * 256 + threadIdx.x;
  int t = idx >> 9;
  int c0 = (idx & 511) << 2;
  float4 v = *reinterpret_cast<const float4*>(X + ((size_t)t << 11) + c0);
  float vv[4] = {v.x, v.y, v.z, v.w};
  int s = sw3(t);
  size_t base = (size_t)t << 11;
#pragma unroll
  for (int j = 0; j < 4; ++j) {
    int c = (c0 + j) ^ s;
    u16 h = f2bf(vv[j]);
    H[base + c] = h;
    L[base + c] = f2bf(vv[j] - bf2f(h));
  }
}

// W [K][N] f32 -> W^T [N][K] bf16 (hi only), column(k)-swizzled by sw3(n)
__global__ void transpose_kernel(const float* __restrict__ W, u16* __restrict__ TH, int K,
                                 int N) {
  __shared__ float tile[64][65];
  int bk = blockIdx.x * 64, bn = blockIdx.y * 64;
  for (int i = threadIdx.x; i < 64 * 64; i += 256) {
    int r = i >> 6, c = i & 63;
    tile[r][c] = W[(size_t)(bk + r) * N + bn + c];
  }
  __syncthreads();
  for (int i = threadIdx.x; i < 64 * 64; i += 256) {
    int r = i >> 6, c = i & 63;
    float v = tile[c][r];
    int n = bn + r, k = bk + c;
    TH[(size_t)n * K + (k ^ sw3(n))] = f2bf(v);
  }
}

// ---------------- bf16x2 GEMM: C = (Ah+Al) @ Bh^T ----------------
// EPI 0: -> qk_h (q plain, k sw7) + vt_h (V^T, sw7 on t).  EPI 1: fp32 -> outp
template <int EPI>
__global__ __launch_bounds__(256, 3) void gemm_bf16x2(
    const u16* __restrict__ Agh, const u16* __restrict__ Agl, const u16* __restrict__ Bgh,
    int N, int K, u16* __restrict__ qk_h, u16* __restrict__ vt_h, float* __restrict__ outp) {
  __shared__ __align__(16) u16 LA[3][128][32];  // Ah, Al, Bh (24 KB)
  const int tid = threadIdx.x;
  const int w = tid >> 6, lane = tid & 63;
  const int lr = lane & 15, kg = lane >> 4;
  const int bn0 = blockIdx.x * 128, bm0 = blockIdx.y * 128;
  const int wm = (w >> 1) * 64, wn = (w & 1) * 64;

  const int srow = lane >> 2;
  const int scol = (lane & 3) << 3;

  f32x4 acc[4][4];
  const f32x4 VZ = {0.f, 0.f, 0.f, 0.f};
#pragma unroll
  for (int m = 0; m < 4; ++m)
#pragma unroll
    for (int n = 0; n < 4; ++n) acc[m][n] = VZ;

  for (int k0 = 0; k0 < K; k0 += 32) {
    __syncthreads();
#pragma unroll
    for (int i = w * 6; i < w * 6 + 6; ++i) {  // 24 chunks of 1KB, 6 per wave
      int a = i >> 3, c = i & 7;
      const u16* src = (a == 0) ? Agh : (a == 1) ? Agl : Bgh;
      int tb = (a < 2) ? bm0 : bn0;
      gload16(src + (size_t)(tb + c * 16 + srow) * K + k0 + scol, &LA[a][c * 16][0]);
    }
    __syncthreads();

    bf16x8 ah[4], al[4], bh[4];
#pragma unroll
    for (int m = 0; m < 4; ++m) {
      int row = wm + m * 16 + lr;
      int off = (row << 5) + ((kg << 3) ^ sw3(row));
      ah[m] = *reinterpret_cast<const bf16x8*>(&LA[0][0][0] + off);
      al[m] = *reinterpret_cast<const bf16x8*>(&LA[1][0][0] + off);
    }
#pragma unroll
    for (int n = 0; n < 4; ++n) {
      int row = wn + n * 16 + lr;
      int off = (row << 5) + ((kg << 3) ^ sw3(row));
      bh[n] = *reinterpret_cast<const bf16x8*>(&LA[2][0][0] + off);
    }
#pragma unroll
    for (int m = 0; m < 4; ++m)
#pragma unroll
      for (int n = 0; n < 4; ++n) {
        acc[m][n] = MFMA16(ah[m], bh[n], acc[m][n]);
        acc[m][n] = MFMA16(al[m], bh[n], acc[m][n]);
      }
  }

#pragma unroll
  for (int m = 0; m < 4; ++m) {
#pragma unroll
    for (int n = 0; n < 4; ++n) {
#pragma unroll
      for (int r = 0; r < 4; ++r) {
        int row = bm0 + wm + m * 16 + (kg << 2) + r;  // C/D: row=(lane>>4)*4+reg
        int col = bn0 + wn + n * 16 + lr;             //      col=lane&15
        float v = acc[m][n][r];
        if (EPI == 0) {
          u16 hh = f2bf(v);
          if (col < 4096) {  // q plain; k sw7-swizzled within 64-col head slice
            int cc = (col < 2048) ? col : (2048 + ((col - 2048) ^ sw7(row)));
            qk_h[((size_t)row << 12) + cc] = hh;
          } else {  // v -> transposed [vc][t], t sw7-swizzled by vc
            int vc = col - 4096;
            vt_h[((size_t)vc << 11) + (row ^ sw7(vc))] = hh;
          }
        } else {
          outp[(size_t)row * N + col] = v;
        }
      }
    }
  }
}

// ---------------- fused dual flash-attention + lambda-combine + RMS norm ----------------
// grid (T/64, 16 heads), 4 waves; wave owns 16 q-rows; KB=64 keys per tile.
__global__ __launch_bounds__(256, 2) void diff_attn_kernel(
    const u16* __restrict__ qk_h, const u16* __restrict__ vt_h, const float* __restrict__ lam_p,
    const float* __restrict__ rms_scale, u16* __restrict__ at_h, u16* __restrict__ at_l) {
  __shared__ __align__(16) u16 KL[2][64][64];     // K1, K2 (16 KB), sw7 on d-chunks
  __shared__ __align__(16) u16 VL[128][64];       // V^T (16 KB), sw7 on t-chunks
  __shared__ __align__(16) u16 PL[4][2][16][64];  // per-wave P hi (16 KB), rotation-swizzled

  const int tid = threadIdx.x;
  const int w = tid >> 6, lane = tid & 63;
  const int lr = lane & 15, kg = lane >> 4;
  const int h = blockIdx.y;
  const int qb = blockIdx.x * 64 + w * 16;
  const float lam = lam_p[0];
  const f32x4 VZ = {0.f, 0.f, 0.f, 0.f};

  // Q fragments (hi only): [stream][kchunk]
  bf16x8 qf[2][2];
  {
    const size_t qrb = ((size_t)(qb + lr)) << 12;
#pragma unroll
    for (int s = 0; s < 2; ++s) {
      int qo = h * 64 + s * 1024;
#pragma unroll
      for (int kc = 0; kc < 2; ++kc)
        qf[s][kc] = *reinterpret_cast<const bf16x8*>(qk_h + qrb + qo + kc * 32 + (kg << 3));
    }
  }

  f32x4 o1[8], o2[8];
#pragma unroll
  for (int n = 0; n < 8; ++n) { o1[n] = VZ; o2[n] = VZ; }
  float m1[4], l1[4], m2[4], l2[4];
#pragma unroll
  for (int r = 0; r < 4; ++r) { m1[r] = m2[r] = -1e30f; l1[r] = l2[r] = 0.f; }

  // staging: wave0->K1, wave1->K2, wave2->V[0:64], wave3->V[64:128]; 8 x 1KB chunks each
  const int srow8 = lane >> 3, scol8 = (lane & 7) << 3;
  const int koff = 2048 + h * 64 + w * 1024;  // valid for w<2

  // online softmax, defer-max THR=8; writes P (bf16 hi) rotation-swizzled into PL[w][sidx]
  auto smx = [&](f32x4 (&sf)[4], float (&m)[4], float (&l)[4], f32x4 (&o)[8], int sidx) {
    float sv[4][4];
#pragma unroll
    for (int n = 0; n < 4; ++n)
#pragma unroll
      for (int r = 0; r < 4; ++r) sv[n][r] = sf[n][r] * 0.125f;  // 1/sqrt(64)
    float tmax[4];
#pragma unroll
    for (int r = 0; r < 4; ++r) {
      float t = fmaxf(fmaxf(sv[0][r], sv[1][r]), fmaxf(sv[2][r], sv[3][r]));
      t = fmaxf(t, __shfl_xor(t, 1, 64));
      t = fmaxf(t, __shfl_xor(t, 2, 64));
      t = fmaxf(t, __shfl_xor(t, 4, 64));
      t = fmaxf(t, __shfl_xor(t, 8, 64));
      tmax[r] = t;
    }
    int need = 0;
#pragma unroll
    for (int r = 0; r < 4; ++r) need |= (tmax[r] > m[r] + 8.f) ? 1 : 0;
    if (__any(need)) {
#pragma unroll
      for (int r = 0; r < 4; ++r) {
        float mn = fmaxf(m[r], tmax[r]);
        float corr = __expf(m[r] - mn);
        m[r] = mn;
        l[r] *= corr;
#pragma unroll
        for (int n = 0; n < 8; ++n) o[n][r] *= corr;
      }
    }
    float ps[4] = {0.f, 0.f, 0.f, 0.f};
#pragma unroll
    for (int n = 0; n < 4; ++n)
#pragma unroll
      for (int r = 0; r < 4; ++r) {
        float p = __expf(sv[n][r] - m[r]);
        ps[r] += p;
        // store at row=4*kg+r, col=n*16+lr, chunk rotated: q'=(n*2+(lr>>3)+kg+2r)&7
        int qp = (n * 2 + (lr >> 3) + kg + 2 * r) & 7;
        PL[w][sidx][4 * kg + r][qp * 8 + (lr & 7)] = f2bf(p);
      }
#pragma unroll
    for (int r = 0; r < 4; ++r) {
      float t = ps[r];
      t += __shfl_xor(t, 1, 64);
      t += __shfl_xor(t, 2, 64);
      t += __shfl_xor(t, 4, 64);
      t += __shfl_xor(t, 8, 64);
      l[r] += t;
    }
  };

  for (int kt = 0; kt < 2048; kt += 64) {
    __syncthreads();  // previous tile's LDS reads complete
    if (w < 2) {
#pragma unroll
      for (int c = 0; c < 8; ++c)
        gload16(qk_h + (((size_t)(kt + c * 8 + srow8)) << 12) + koff + scol8, &KL[w][c * 8][0]);
    } else {
      int vb = (w - 2) * 64;
#pragma unroll
      for (int c = 0; c < 8; ++c)
        gload16(vt_h + (((size_t)(h * 128 + vb + c * 8 + srow8)) << 11) + kt + scol8,
                &VL[vb + c * 8][0]);
    }
    __syncthreads();  // staging drained

    // S = Q K^T (1 term)
    f32x4 s1[4], s2[4];
#pragma unroll
    for (int n = 0; n < 4; ++n) { s1[n] = VZ; s2[n] = VZ; }
#pragma unroll
    for (int n = 0; n < 4; ++n) {
      int key = n * 16 + lr;
#pragma unroll
      for (int kc = 0; kc < 2; ++kc) {
        int off = (key << 6) + (((kc << 5) + (kg << 3)) ^ sw7(key));
        bf16x8 k1 = *reinterpret_cast<const bf16x8*>(&KL[0][0][0] + off);
        bf16x8 k2 = *reinterpret_cast<const bf16x8*>(&KL[1][0][0] + off);
        s1[n] = MFMA16(qf[0][kc], k1, s1[n]);
        s2[n] = MFMA16(qf[1][kc], k2, s2[n]);
      }
    }

    smx(s1, m1, l1, o1, 0);
    smx(s2, m2, l2, o2, 1);

    // O += P V (1 term); V fragments shared across streams
    bf16x8 pa1[2], pa2[2];
#pragma unroll
    for (int ks = 0; ks < 2; ++ks) {
      int qp = (ks * 4 + kg + (lr >> 2) + 2 * (lr & 3)) & 7;
      pa1[ks] = *reinterpret_cast<const bf16x8*>(&PL[w][0][lr][qp * 8]);
      pa2[ks] = *reinterpret_cast<const bf16x8*>(&PL[w][1][lr][qp * 8]);
    }
#pragma unroll
    for (int n = 0; n < 8; ++n) {
      int vd = n * 16 + lr;
#pragma unroll
      for (int ks = 0; ks < 2; ++ks) {
        int off = (vd << 6) + (((ks << 5) + (kg << 3)) ^ sw7(vd));
        bf16x8 vf = *reinterpret_cast<const bf16x8*>(&VL[0][0] + off);
        o1[n] = MFMA16(pa1[ks], vf, o1[n]);
        o2[n] = MFMA16(pa2[ks], vf, o2[n]);
      }
    }
  }

  // epilogue: a1 - lam*a2, RMS over 128, * rms_scale * (1-LAMBDA_INIT); hi/lo split for GEMM2
  float nsc[4];
  {
    float il1[4], il2[4], ss[4];
#pragma unroll
    for (int r = 0; r < 4; ++r) { il1[r] = 1.f / l1[r]; il2[r] = 1.f / l2[r]; ss[r] = 0.f; }
#pragma unroll
    for (int n = 0; n < 8; ++n)
#pragma unroll
      for (int r = 0; r < 4; ++r) {
        float v = o1[n][r] * il1[r] - lam * (o2[n][r] * il2[r]);
        o1[n][r] = v;
        ss[r] += v * v;
      }
#pragma unroll
    for (int r = 0; r < 4; ++r) {
      float t = ss[r];
      t += __shfl_xor(t, 1, 64);
      t += __shfl_xor(t, 2, 64);
      t += __shfl_xor(t, 4, 64);
      t += __shfl_xor(t, 8, 64);
      nsc[r] = rsqrtf(t * (1.f / 128.f) + 1e-6f) * ONE_MINUS_LI_F;
    }
  }
#pragma unroll
  for (int n = 0; n < 8; ++n) {
    float rs = rms_scale[n * 16 + lr];
#pragma unroll
    for (int r = 0; r < 4; ++r) {
      int row = qb + (kg << 2) + r;
      int col = h * 128 + n * 16 + lr;
      float v = o1[n][r] * nsc[r] * rs;
      u16 hh = f2bf(v);
      int cc = col ^ sw3(row);
      at_h[((size_t)row << 11) + cc] = hh;
      at_l[((size_t)row << 11) + cc] = f2bf(v - bf2f(hh));
    }
  }
}

// ---------------- launch ----------------

extern "C" void kernel_launch(void* const* d_in, const int* in_sizes, int n_in, void* d_out,
                              int out_size, void* d_ws, size_t ws_size, hipStream_t stream) {
  (void)in_sizes; (void)n_in; (void)out_size;
  const float* x = (const float*)d_in[0];
  const float* wqkv = (const float*)d_in[1];
  const float* wprj = (const float*)d_in[2];
  const float* lq1 = (const float*)d_in[3];
  const float* lk1 = (const float*)d_in[4];
  const float* lq2 = (const float*)d_in[5];
  const float* lk2 = (const float*)d_in[6];
  const float* rms = (const float*)d_in[7];
  float* out = (float*)d_out;

  char* p = (char*)d_ws;
  auto take = [&](size_t n) { char* r = p; p += (n + 255) & ~(size_t)255; return r; };
  float* lam = (float*)take(256);
  u16* x_h = (u16*)take(2048ull * 2048 * 2);
  u16* x_l = (u16*)take(2048ull * 2048 * 2);
  u16* wqT_h = (u16*)take(6144ull * 2048 * 2);
  u16* wpT_h = (u16*)take(2048ull * 2048 * 2);
  u16* qk_h = (u16*)take(2048ull * 4096 * 2);
  u16* vt_h = (u16*)take(2048ull * 2048 * 2);
  u16* at_h = (u16*)take(2048ull * 2048 * 2);
  u16* at_l = (u16*)take(2048ull * 2048 * 2);
  if ((size_t)(p - (char*)d_ws) > ws_size) return;

  lam_kernel<<<1, 64, 0, stream>>>(lq1, lk1, lq2, lk2, lam);
  split_x_kernel<<<4096, 256, 0, stream>>>(x, x_h, x_l);
  transpose_kernel<<<dim3(32, 96), 256, 0, stream>>>(wqkv, wqT_h, 2048, 6144);
  transpose_kernel<<<dim3(32, 32), 256, 0, stream>>>(wprj, wpT_h, 2048, 2048);

  // qkv = x @ w_qkv (M=2048, N=6144, K=2048) -> qk_h + vt_h
  gemm_bf16x2<0><<<dim3(48, 16), 256, 0, stream>>>(x_h, x_l, wqT_h, 6144, 2048, qk_h, vt_h,
                                                   nullptr);
  // dual flash attention + combine + RMS
  diff_attn_kernel<<<dim3(32, 16), 256, 0, stream>>>(qk_h, vt_h, lam, rms, at_h, at_l);
  // out = attn @ w_proj (M=N=K=2048), fp32 out
  gemm_bf16x2<1><<<dim3(16, 16), 256, 0, stream>>>(at_h, at_l, wpT_h, 2048, 2048, nullptr,
                                                   nullptr, out);
}